// Round 12
// baseline (115.067 us; speedup 1.0000x reference)
//
#include <hip/hip_runtime.h>
#include <hip/hip_bf16.h>

#define N_NODES 20000
#define N_PAD   20096          // 157 * 128 = 314 * 64
#define N_EDGES 320000
#define D_IN    256
#define NEG     0.2f
#define MAXDEG  64
#define NSB     64             // superblocks for counting sort
#define EPSB    5000           // edges per superblock (64*5000 = 320000 exactly)
#define NBIN    313            // coarse bins: dst>>6

typedef __attribute__((ext_vector_type(8))) short short8;
typedef __attribute__((ext_vector_type(4))) float f32x4;
typedef __attribute__((ext_vector_type(4))) unsigned short u16x4;

__device__ __forceinline__ unsigned short f2b(float f) {
    unsigned int u = __float_as_uint(f);
    unsigned int r = (u + 0x7FFFu + ((u >> 16) & 1u)) >> 16;   // RNE
    return (unsigned short)r;
}
__device__ __forceinline__ float b2f(unsigned short u) {
    union { unsigned int i; float f; } v;
    v.i = ((unsigned int)u) << 16;
    return v.f;
}

__device__ __forceinline__ void gload16(const void* g, void* l) {
    __builtin_amdgcn_global_load_lds((const __attribute__((address_space(1))) void*)g,
                                     (__attribute__((address_space(3))) void*)l, 16, 0, 0);
}

// ---------------- fused prep: cvt_x + cvt_wt + cvt_wt2 + sort-pass1 hist + zero(yb pad) ----------------
#define PB1 2512
#define PB2 3280
#define PB3 3376
#define PB4 3440
#define PREP_BLOCKS 3488
__global__ __launch_bounds__(256) void k_prep(
    const float* __restrict__ x, unsigned short* __restrict__ xb,
    const float* __restrict__ Ws1, const float* __restrict__ Wd1, const float* __restrict__ Wr1,
    unsigned short* __restrict__ wt,
    const float* __restrict__ Ws2, const float* __restrict__ Wd2, const float* __restrict__ Wr2,
    unsigned short* __restrict__ wt2,
    const int* __restrict__ dst, int* __restrict__ blockhist,
    unsigned short* __restrict__ yb)
{
    int bid = blockIdx.x, tid = threadIdx.x;
    if (bid < PB1) {                                    // x -> xb bf16
        int i = bid * 256 + tid;
        int row = i >> 5, c8 = (i & 31) * 8;
        short8 v = {0, 0, 0, 0, 0, 0, 0, 0};
        if (row < N_NODES) {
            float4 a = *reinterpret_cast<const float4*>(x + (size_t)row * 256 + c8);
            float4 b = *reinterpret_cast<const float4*>(x + (size_t)row * 256 + c8 + 4);
            v[0] = (short)f2b(a.x); v[1] = (short)f2b(a.y); v[2] = (short)f2b(a.z); v[3] = (short)f2b(a.w);
            v[4] = (short)f2b(b.x); v[5] = (short)f2b(b.y); v[6] = (short)f2b(b.z); v[7] = (short)f2b(b.w);
        }
        *reinterpret_cast<short8*>(xb + (size_t)row * 256 + c8) = v;
    } else if (bid < PB2) {                             // WT [768][256]
        int n = bid - PB1, k = tid;
        const float* W = (n < 256) ? Ws1 : ((n < 512) ? Wd1 : Wr1);
        int c = n & 255;
        wt[(size_t)n * 256 + k] = f2b(W[(size_t)k * 256 + c]);
    } else if (bid < PB3) {                             // WT2 [96][256], pre-swizzled
        int n = bid - PB2, k = tid;
        const float* W = (n < 32) ? Ws2 : ((n < 64) ? Wd2 : Wr2);
        int c = n & 31;
        wt2[(size_t)n * 256 + (k ^ ((n & 7) << 3))] = f2b(W[(size_t)k * 32 + c]);
    } else if (bid < PB4) {                             // per-superblock coarse histogram
        __shared__ int hist[NBIN];
        int blk = bid - PB3;
        for (int b = tid; b < NBIN; b += 256) hist[b] = 0;
        __syncthreads();
        for (int it = 0; it < 20; ++it) {
            int li = it * 256 + tid;
            if (li < EPSB) atomicAdd(&hist[dst[blk * EPSB + li] >> 6], 1);
        }
        __syncthreads();
        for (int b = tid; b < NBIN; b += 256) blockhist[blk * NBIN + b] = hist[b];
    } else {                                            // zero yb pad rows
        int j = (bid - PB4) * 256 + tid;
        ((unsigned int*)(yb + (size_t)N_NODES * 256))[j] = 0u;
    }
}

// ---------------- sort pass 3 (integrated per-block scan): edges -> bin-contiguous sorted[] ----------------
__global__ __launch_bounds__(320) void k_pass3(
    const int* __restrict__ src, const int* __restrict__ dst,
    const int* __restrict__ blockhist,
    unsigned long long* __restrict__ sorted,
    int* __restrict__ binbase_g, int* __restrict__ bintotal_g)
{
    __shared__ int tmp[320];
    __shared__ int binbase[NBIN];
    __shared__ int rank[NBIN];
    int blk = blockIdx.x, tid = threadIdx.x;
    int mystart = 0, total = 0;
    if (tid < NBIN) {
        for (int b = 0; b < NSB; ++b) {
            int v = blockhist[b * NBIN + tid];
            total += v;
            if (b < blk) mystart += v;
        }
    }
    tmp[tid] = (tid < NBIN) ? total : 0;
    __syncthreads();
    for (int off = 1; off < 320; off <<= 1) {           // Hillis-Steele inclusive scan
        int v = (tid >= off) ? tmp[tid - off] : 0;
        __syncthreads();
        tmp[tid] += v;
        __syncthreads();
    }
    if (tid < NBIN) {
        int excl = tmp[tid] - total;
        binbase[tid] = excl;
        rank[tid] = mystart;
        if (blk == 0) { binbase_g[tid] = excl; bintotal_g[tid] = total; }
    }
    __syncthreads();
    for (int it = 0; it < 16; ++it) {
        int li = it * 320 + tid;
        if (li < EPSB) {
            int e = blk * EPSB + li;
            int d = dst[e];
            int b = d >> 6;
            int r = atomicAdd(&rank[b], 1);             // LDS atomic
            sorted[binbase[b] + r] = ((unsigned long long)(unsigned)d << 32) | (unsigned)src[e];
        }
    }
}

// ---------------- Layer-1 MFMA GEMM (1884 blocks, 64x128 tile, dbuf) + sort-pass4 tail (313) ----------------
#define GEMM1_BLOCKS 1884
#define PASS4_BLOCKS 313
__global__ __launch_bounds__(256) void k_gemm_l1_mfma(
    const unsigned short* __restrict__ xb,   // [N_PAD][256] bf16
    const unsigned short* __restrict__ wt,   // [768][256] bf16
    const float* __restrict__ bs, const float* __restrict__ bd, const float* __restrict__ br,
    unsigned short* __restrict__ fs, unsigned short* __restrict__ fd, unsigned short* __restrict__ res,
    const unsigned long long* __restrict__ sorted,
    const int* __restrict__ binbase_g, const int* __restrict__ bintotal_g,
    int* __restrict__ colp, int* __restrict__ cnt)
{
    __shared__ __align__(16) unsigned short SH[12288];  // 24KB: 2 x (As 4KB | Bs 8KB); C-tile 16KB
    int t = threadIdx.x;
    int bid = blockIdx.x;

    if (bid >= GEMM1_BLOCKS) {                  // ---- pass4 tail: per-bin node bucketing ----
        int* ch = (int*)SH;
        int nb2 = bid - GEMM1_BLOCKS;
        if (t < 64) ch[t] = 0;
        __syncthreads();
        int base = binbase_g[nb2], tot = bintotal_g[nb2];
        for (int i = t; i < tot; i += 256) {
            unsigned long long p = sorted[base + i];
            int d = (int)(p >> 32);
            int s = (int)(p & 0xffffffffULL);
            int r = atomicAdd(&ch[d & 63], 1);          // LDS atomic
            if (r < MAXDEG) colp[(size_t)d * MAXDEG + r] = s;
        }
        __syncthreads();
        int node = nb2 * 64 + t;
        if (t < 64 && node < N_NODES) cnt[node] = ch[t];
        return;
    }

    int lane = t & 63, w = t >> 6;
    // bijective XCD swizzle (m204): 1884 = 8*235 + 4
    const int q = 235, r = 4;
    int xcd = bid & 7, slot = bid >> 3;
    int wg = (xcd < r ? xcd * (q + 1) : r * (q + 1) + (xcd - r) * q) + slot;
    int mb = wg / 6, nb = wg % 6;
    int row0 = mb * 64;
    int which = nb >> 1;
    int col0 = (nb & 1) * 128;
    int ncol0 = nb * 128;
    unsigned short* out = (which == 0) ? fs : ((which == 1) ? fd : res);
    const float* bias   = (which == 0) ? bs : ((which == 1) ? bd : br);

    auto stage = [&](int buf, int k0) {
        char* base = (char*)SH + buf * 12288;
        {   // As: 64 rows x 32 k = 256 chunks
            int c = t, row = c >> 2, kc = (c & 3) * 8;
            gload16(xb + (size_t)(row0 + row) * 256 + k0 + kc, base + c * 16);
        }
#pragma unroll
        for (int r2 = 0; r2 < 2; r2++) {  // Bs: 128 rows x 32 k = 512 chunks
            int c = r2 * 256 + t, row = c >> 2, kc = (c & 3) * 8;
            gload16(wt + (size_t)(ncol0 + row) * 256 + k0 + kc, base + 4096 + c * 16);
        }
    };

    f32x4 acc[4][2] = {};

    stage(0, 0);
    __syncthreads();
    int cur = 0;
#pragma unroll
    for (int it = 0; it < 8; ++it) {
        if (it < 7) stage(cur ^ 1, (it + 1) * 32);   // issue next tile BEFORE compute
        const char* Ab = (const char*)SH + cur * 12288;
        const char* Bb = Ab + 4096;
        short8 a[4], b[2];
#pragma unroll
        for (int m = 0; m < 4; m++)
            a[m] = *reinterpret_cast<const short8*>(Ab + ((m * 16 + (lane & 15)) * 64 + (lane >> 4) * 16));
#pragma unroll
        for (int n = 0; n < 2; n++)
            b[n] = *reinterpret_cast<const short8*>(Bb + ((w * 32 + n * 16 + (lane & 15)) * 64 + (lane >> 4) * 16));
#pragma unroll
        for (int m = 0; m < 4; m++)
#pragma unroll
            for (int n = 0; n < 2; n++)
                acc[m][n] = __builtin_amdgcn_mfma_f32_16x16x32_bf16(a[m], b[n], acc[m][n], 0, 0, 0);
        __syncthreads();
        cur ^= 1;
    }

    // ---- epilogue: LDS-staged coalesced bf16 C-write (64 rows x 256B), single pass ----
    int cgrp = lane >> 4, ccol = lane & 15;
    float bvals[2];
#pragma unroll
    for (int n = 0; n < 2; n++) bvals[n] = bias[col0 + w * 32 + n * 16 + ccol];

#pragma unroll
    for (int m = 0; m < 4; m++)
#pragma unroll
        for (int n = 0; n < 2; n++)
#pragma unroll
            for (int q2 = 0; q2 < 4; q2++) {
                int lr = m * 16 + cgrp * 4 + q2;                     // 0..63
                int cb = (w * 32 + n * 16 + ccol) * 2;               // col byte 0..255
                int addr = lr * 256 + (cb ^ (cgrp << 5));            // bank-spread XOR
                *(unsigned short*)((char*)SH + addr) = f2b(acc[m][n][q2] + bvals[n]);
            }
    __syncthreads();
#pragma unroll
    for (int it = 0; it < 4; it++) {
        int lr = it * 16 + (t >> 4);                                 // 0..63
        int cb = (t & 15) * 16;
        short8 v = *(const short8*)((const char*)SH + (lr * 256 + (cb ^ (((lr >> 2) & 3) << 5))));
        int gr = row0 + lr;
        if (gr < N_NODES)
            *reinterpret_cast<short8*>(out + (size_t)gr * 256 + col0 + (t & 15) * 8) = v;
    }
}

// ---------------- Layer-1 gather: 4 nodes per 256-thread block (1 wave/node), online softmax ----------------
__global__ __launch_bounds__(256) void k_gather_l1(
    const int* __restrict__ cnt, const int* __restrict__ colp,
    const unsigned short* __restrict__ fs1, const unsigned short* __restrict__ fd1,
    const unsigned short* __restrict__ res1, const float* __restrict__ attn1,
    unsigned short* __restrict__ y)
{
    int n = blockIdx.x * 4 + (threadIdx.x >> 6);
    int l = threadIdx.x & 63;     // lane: dims [4l,4l+4), head = l>>3
    u16x4 fdv4 = *reinterpret_cast<const u16x4*>(fd1 + (size_t)n * 256 + l * 4);
    float fdv[4] = {b2f(fdv4[0]), b2f(fdv4[1]), b2f(fdv4[2]), b2f(fdv4[3])};
    float4 attv = *reinterpret_cast<const float4*>(attn1 + l * 4);
    float att[4] = {attv.x, attv.y, attv.z, attv.w};

    const int* colrow = colp + (size_t)n * MAXDEG;
    int deg = cnt[n];
    if (deg > MAXDEG) deg = MAXDEG;

    float m = -1e30f, s = 0.f;
    float acc[4] = {0.f, 0.f, 0.f, 0.f};
    int c0 = (0 < deg) ? colrow[0] : 0;
    int c1 = (1 < deg) ? colrow[1] : 0;
    u16x4 f0 = *reinterpret_cast<const u16x4*>(fs1 + (size_t)c0 * 256 + l * 4);
    u16x4 f1 = *reinterpret_cast<const u16x4*>(fs1 + (size_t)c1 * 256 + l * 4);
    for (int idx = 0; idx < deg; ++idx) {
        u16x4 fv4 = f0;
        f0 = f1;
        int c2 = (idx + 2 < deg) ? colrow[idx + 2] : 0;   // clamped -> always in-bounds
        f1 = *reinterpret_cast<const u16x4*>(fs1 + (size_t)c2 * 256 + l * 4);
        float fv[4] = {b2f(fv4[0]), b2f(fv4[1]), b2f(fv4[2]), b2f(fv4[3])};
        float t0 = fv[0] + fdv[0]; t0 = t0 > 0.f ? t0 : NEG * t0;
        float t1 = fv[1] + fdv[1]; t1 = t1 > 0.f ? t1 : NEG * t1;
        float t2 = fv[2] + fdv[2]; t2 = t2 > 0.f ? t2 : NEG * t2;
        float t3 = fv[3] + fdv[3]; t3 = t3 > 0.f ? t3 : NEG * t3;
        float p = t0 * att[0] + t1 * att[1] + t2 * att[2] + t3 * att[3];
        p += __shfl_xor(p, 1);
        p += __shfl_xor(p, 2);
        p += __shfl_xor(p, 4);
        float mn = fmaxf(m, p);
        float e  = __expf(p - mn);
        float sc = __expf(m - mn);
        s = s * sc + e;
        acc[0] = acc[0] * sc + e * fv[0];
        acc[1] = acc[1] * sc + e * fv[1];
        acc[2] = acc[2] * sc + e * fv[2];
        acc[3] = acc[3] * sc + e * fv[3];
        m = mn;
    }
    u16x4 rv4 = *reinterpret_cast<const u16x4*>(res1 + (size_t)n * 256 + l * 4);
    float inv = (s > 0.f) ? 1.f / s : 0.f;
    u16x4 o;
    o[0] = f2b(fmaxf(acc[0] * inv + b2f(rv4[0]), 0.f));
    o[1] = f2b(fmaxf(acc[1] * inv + b2f(rv4[1]), 0.f));
    o[2] = f2b(fmaxf(acc[2] * inv + b2f(rv4[2]), 0.f));
    o[3] = f2b(fmaxf(acc[3] * inv + b2f(rv4[3]), 0.f));
    *reinterpret_cast<u16x4*>(y + (size_t)n * 256 + l * 4) = o;
}

// ---------------- Layer-2 MFMA GEMM: 64-row tiles, 2-phase dbuf A, B resident ----------------
__global__ __launch_bounds__(256) void k_gemm_l2_mfma(
    const unsigned short* __restrict__ yb,   // [N_PAD][256] bf16
    const unsigned short* __restrict__ wt2,  // [96][256] bf16, pre-swizzled
    const float* __restrict__ bs, const float* __restrict__ bd, const float* __restrict__ br,
    unsigned short* __restrict__ fs2, unsigned short* __restrict__ fd2, unsigned short* __restrict__ res2)
{
    __shared__ __align__(16) unsigned short Bs[96 * 256];   // 48 KB, whole WT2
    __shared__ __align__(16) unsigned short As[2][64 * 32]; // 2 x 4 KB
    int t = threadIdx.x;
    int lane = t & 63, w = t >> 6;
    int row0 = blockIdx.x * 64;

    auto stage_a = [&](int buf, int k0) {
        int c = t;
        int row = c >> 2, kc = (c & 3) * 8;
        gload16(yb + (size_t)(row0 + row) * 256 + k0 + kc, (char*)As[buf] + c * 16);
    };

#pragma unroll
    for (int i = 0; i < 12; i++) {
        int c = i * 256 + t;
        gload16(wt2 + (size_t)c * 8, (char*)Bs + (size_t)c * 16);
    }
    stage_a(0, 0);
    __syncthreads();

    f32x4 acc[6] = {};
    int arow0 = w * 16;
    int cur = 0;

#pragma unroll
    for (int it = 0; it < 8; ++it) {
        if (it < 7) stage_a(cur ^ 1, (it + 1) * 32);
        short8 a = *reinterpret_cast<const short8*>((const char*)As[cur] + ((arow0 + (lane & 15)) * 64 + (lane >> 4) * 16));
        short8 b[6];
#pragma unroll
        for (int n = 0; n < 6; n++) {
            int brow = n * 16 + (lane & 15);
            int kbyte = (it * 32 + (lane >> 4) * 8) * 2;
            b[n] = *reinterpret_cast<const short8*>((const char*)Bs + (brow * 512 + (kbyte ^ ((brow & 7) << 4))));
        }
#pragma unroll
        for (int n = 0; n < 6; n++)
            acc[n] = __builtin_amdgcn_mfma_f32_16x16x32_bf16(a, b[n], acc[n], 0, 0, 0);
        __syncthreads();
        cur ^= 1;
    }

    int cgrp = lane >> 4, ccol = lane & 15;
#pragma unroll
    for (int n = 0; n < 6; n++) {
        int which = n >> 1;
        int cc = (n & 1) * 16 + ccol;
        unsigned short* out = (which == 0) ? fs2 : ((which == 1) ? fd2 : res2);
        const float* bias   = (which == 0) ? bs  : ((which == 1) ? bd  : br);
        float bv = bias[cc];
        int rbase = row0 + arow0 + cgrp * 4;
#pragma unroll
        for (int q2 = 0; q2 < 4; q2++) {
            int rr = rbase + q2;
            if (rr < N_NODES) out[(size_t)rr * 32 + cc] = f2b(acc[n][q2] + bv);
        }
    }
}

// ---------------- Layer-2 gather: 4 nodes per 256-thread block (1 wave/node), prefetched ----------------
__global__ __launch_bounds__(256) void k_gather_l2(
    const int* __restrict__ cnt, const int* __restrict__ colp,
    const unsigned short* __restrict__ fs2, const unsigned short* __restrict__ fd2,
    const unsigned short* __restrict__ res2, const float* __restrict__ attn2,
    float* __restrict__ out)
{
    int n = blockIdx.x * 4 + (threadIdx.x >> 6);
    int l = threadIdx.x & 63;
    int d = l & 31, h = l >> 5;
    float fdv = b2f(fd2[(size_t)n * 32 + d]);
    float att = attn2[d];
    const int* colrow = colp + (size_t)n * MAXDEG;
    int deg = cnt[n];
    if (deg > MAXDEG) deg = MAXDEG;

    float m = -1e30f, s = 0.f, acc = 0.f;
    int c0 = (h < deg) ? colrow[h] : 0;
    float fv_next = b2f(fs2[(size_t)c0 * 32 + d]);
    for (int i = h; i < deg; i += 2) {
        float fv = fv_next;
        int cn = (i + 2 < deg) ? colrow[i + 2] : 0;
        fv_next = b2f(fs2[(size_t)cn * 32 + d]);
        float t0 = fv + fdv; t0 = t0 > 0.f ? t0 : NEG * t0;
        float p = t0 * att;
        p += __shfl_xor(p, 1);
        p += __shfl_xor(p, 2);
        p += __shfl_xor(p, 4);
        p += __shfl_xor(p, 8);
        p += __shfl_xor(p, 16);
        float mn = fmaxf(m, p);
        float e  = __expf(p - mn);
        float sc = __expf(m - mn);
        s = s * sc + e;
        acc = acc * sc + e * fv;
        m = mn;
    }
    float mo = __shfl_xor(m, 32);
    float mstar = fmaxf(m, mo);
    float myc = __expf(m - mstar);
    float sp = s * myc, ap = acc * myc;
    float st = sp + __shfl_xor(sp, 32);
    float at = ap + __shfl_xor(ap, 32);
    if (l < 32) {
        float rv = b2f(res2[(size_t)n * 32 + d]);
        float inv = (st > 0.f) ? 1.f / st : 0.f;
        out[(size_t)n * 32 + d] = at * inv + rv;
    }
}

extern "C" void kernel_launch(void* const* d_in, const int* in_sizes, int n_in,
                              void* d_out, int out_size, void* d_ws, size_t ws_size,
                              hipStream_t stream)
{
    const float* x   = (const float*)d_in[0];
    const int*   src = (const int*)d_in[1];
    const int*   dst = (const int*)d_in[2];
    const float* Ws1 = (const float*)d_in[3];
    const float* bs1 = (const float*)d_in[4];
    const float* Wd1 = (const float*)d_in[5];
    const float* bd1 = (const float*)d_in[6];
    const float* at1 = (const float*)d_in[7];
    const float* Wr1 = (const float*)d_in[8];
    const float* br1 = (const float*)d_in[9];
    const float* Ws2 = (const float*)d_in[10];
    const float* bs2 = (const float*)d_in[11];
    const float* Wd2 = (const float*)d_in[12];
    const float* bd2 = (const float*)d_in[13];
    const float* at2 = (const float*)d_in[14];
    const float* Wr2 = (const float*)d_in[15];
    const float* br2 = (const float*)d_in[16];
    float* out = (float*)d_out;

    char* w = (char*)d_ws;
    size_t off = 0;
    auto alloc = [&](size_t bytes) { void* p = w + off; off += (bytes + 255) & ~(size_t)255; return p; };
    int*   cnt       = (int*)  alloc((size_t)N_NODES * 4);
    int*   colp      = (int*)  alloc((size_t)N_NODES * MAXDEG * 4);
    int*   blockhist = (int*)  alloc((size_t)NSB * NBIN * 4);
    int*   bintotal  = (int*)  alloc((size_t)NBIN * 4);
    int*   binbase   = (int*)  alloc((size_t)NBIN * 4);
    unsigned long long* sorted = (unsigned long long*)alloc((size_t)N_EDGES * 8);
    unsigned short* fs1 = (unsigned short*)alloc((size_t)N_NODES * 256 * 2);
    unsigned short* fd1 = (unsigned short*)alloc((size_t)N_NODES * 256 * 2);
    unsigned short* res1= (unsigned short*)alloc((size_t)N_NODES * 256 * 2);
    unsigned short* fs2 = (unsigned short*)alloc((size_t)N_NODES * 32 * 2);
    unsigned short* fd2 = (unsigned short*)alloc((size_t)N_NODES * 32 * 2);
    unsigned short* res2= (unsigned short*)alloc((size_t)N_NODES * 32 * 2);
    unsigned short* xb  = (unsigned short*)alloc((size_t)N_PAD * 256 * 2);
    unsigned short* yb  = (unsigned short*)alloc((size_t)N_PAD * 256 * 2);
    unsigned short* wt  = (unsigned short*)alloc((size_t)768 * 256 * 2);
    unsigned short* wt2 = (unsigned short*)alloc((size_t)96 * 256 * 2);
    (void)ws_size; (void)in_sizes; (void)n_in; (void)out_size;

    k_prep<<<PREP_BLOCKS, 256, 0, stream>>>(x, xb, Ws1, Wd1, Wr1, wt, Ws2, Wd2, Wr2, wt2,
                                            dst, blockhist, yb);
    k_pass3<<<NSB, 320, 0, stream>>>(src, dst, blockhist, sorted, binbase, bintotal);
    k_gemm_l1_mfma<<<GEMM1_BLOCKS + PASS4_BLOCKS, 256, 0, stream>>>(
        xb, wt, bs1, bd1, br1, fs1, fd1, res1, sorted, binbase, bintotal, colp, cnt);
    k_gather_l1<<<N_NODES / 4, 256, 0, stream>>>(cnt, colp, fs1, fd1, res1, at1, yb);
    k_gemm_l2_mfma<<<N_PAD / 64, 256, 0, stream>>>(yb, wt2, bs2, bd2, br2, fs2, fd2, res2);
    k_gather_l2<<<N_NODES / 4, 256, 0, stream>>>(cnt, colp, fs2, fd2, res2, at2, out);
}

// Round 13
// 107.123 us; speedup vs baseline: 1.0742x; 1.0742x over previous
//
#include <hip/hip_runtime.h>
#include <hip/hip_bf16.h>

#define N_NODES 20000
#define N_PAD   20096          // 157 * 128 = 314 * 64
#define N_EDGES 320000
#define D_IN    256
#define NEG     0.2f
#define MAXDEG  64
#define NSB     64             // superblocks for counting sort
#define EPSB    5000           // edges per superblock (64*5000 = 320000 exactly)
#define NBIN    313            // coarse bins: dst>>6

typedef __attribute__((ext_vector_type(8))) short short8;
typedef __attribute__((ext_vector_type(4))) float f32x4;
typedef __attribute__((ext_vector_type(4))) unsigned short u16x4;

__device__ __forceinline__ unsigned short f2b(float f) {
    unsigned int u = __float_as_uint(f);
    unsigned int r = (u + 0x7FFFu + ((u >> 16) & 1u)) >> 16;   // RNE
    return (unsigned short)r;
}
__device__ __forceinline__ float b2f(unsigned short u) {
    union { unsigned int i; float f; } v;
    v.i = ((unsigned int)u) << 16;
    return v.f;
}

__device__ __forceinline__ void gload16(const void* g, void* l) {
    __builtin_amdgcn_global_load_lds((const __attribute__((address_space(1))) void*)g,
                                     (__attribute__((address_space(3))) void*)l, 16, 0, 0);
}

// ---------------- fused prep: cvt_x + cvt_wt + cvt_wt2 + sort-pass1 hist + zero(yb pad) ----------------
#define PB1 2512
#define PB2 3280
#define PB3 3376
#define PB4 3440
#define PREP_BLOCKS 3488
__global__ __launch_bounds__(256) void k_prep(
    const float* __restrict__ x, unsigned short* __restrict__ xb,
    const float* __restrict__ Ws1, const float* __restrict__ Wd1, const float* __restrict__ Wr1,
    unsigned short* __restrict__ wt,
    const float* __restrict__ Ws2, const float* __restrict__ Wd2, const float* __restrict__ Wr2,
    unsigned short* __restrict__ wt2,
    const int* __restrict__ dst, int* __restrict__ blockhist,
    unsigned short* __restrict__ yb)
{
    int bid = blockIdx.x, tid = threadIdx.x;
    if (bid < PB1) {                                    // x -> xb bf16
        int i = bid * 256 + tid;
        int row = i >> 5, c8 = (i & 31) * 8;
        short8 v = {0, 0, 0, 0, 0, 0, 0, 0};
        if (row < N_NODES) {
            float4 a = *reinterpret_cast<const float4*>(x + (size_t)row * 256 + c8);
            float4 b = *reinterpret_cast<const float4*>(x + (size_t)row * 256 + c8 + 4);
            v[0] = (short)f2b(a.x); v[1] = (short)f2b(a.y); v[2] = (short)f2b(a.z); v[3] = (short)f2b(a.w);
            v[4] = (short)f2b(b.x); v[5] = (short)f2b(b.y); v[6] = (short)f2b(b.z); v[7] = (short)f2b(b.w);
        }
        *reinterpret_cast<short8*>(xb + (size_t)row * 256 + c8) = v;
    } else if (bid < PB2) {                             // WT [768][256]
        int n = bid - PB1, k = tid;
        const float* W = (n < 256) ? Ws1 : ((n < 512) ? Wd1 : Wr1);
        int c = n & 255;
        wt[(size_t)n * 256 + k] = f2b(W[(size_t)k * 256 + c]);
    } else if (bid < PB3) {                             // WT2 [96][256], pre-swizzled
        int n = bid - PB2, k = tid;
        const float* W = (n < 32) ? Ws2 : ((n < 64) ? Wd2 : Wr2);
        int c = n & 31;
        wt2[(size_t)n * 256 + (k ^ ((n & 7) << 3))] = f2b(W[(size_t)k * 32 + c]);
    } else if (bid < PB4) {                             // per-superblock coarse histogram
        __shared__ int hist[NBIN];
        int blk = bid - PB3;
        for (int b = tid; b < NBIN; b += 256) hist[b] = 0;
        __syncthreads();
        for (int it = 0; it < 20; ++it) {
            int li = it * 256 + tid;
            if (li < EPSB) atomicAdd(&hist[dst[blk * EPSB + li] >> 6], 1);
        }
        __syncthreads();
        for (int b = tid; b < NBIN; b += 256) blockhist[blk * NBIN + b] = hist[b];
    } else {                                            // zero yb pad rows
        int j = (bid - PB4) * 256 + tid;
        ((unsigned int*)(yb + (size_t)N_NODES * 256))[j] = 0u;
    }
}

// ---------------- sort pass 3 (integrated per-block scan): edges -> bin-contiguous sorted[] ----------------
__global__ __launch_bounds__(320) void k_pass3(
    const int* __restrict__ src, const int* __restrict__ dst,
    const int* __restrict__ blockhist,
    unsigned long long* __restrict__ sorted,
    int* __restrict__ binbase_g, int* __restrict__ bintotal_g)
{
    __shared__ int tmp[320];
    __shared__ int binbase[NBIN];
    __shared__ int rank[NBIN];
    int blk = blockIdx.x, tid = threadIdx.x;
    int mystart = 0, total = 0;
    if (tid < NBIN) {
        for (int b = 0; b < NSB; ++b) {
            int v = blockhist[b * NBIN + tid];
            total += v;
            if (b < blk) mystart += v;
        }
    }
    tmp[tid] = (tid < NBIN) ? total : 0;
    __syncthreads();
    for (int off = 1; off < 320; off <<= 1) {           // Hillis-Steele inclusive scan
        int v = (tid >= off) ? tmp[tid - off] : 0;
        __syncthreads();
        tmp[tid] += v;
        __syncthreads();
    }
    if (tid < NBIN) {
        int excl = tmp[tid] - total;
        binbase[tid] = excl;
        rank[tid] = mystart;
        if (blk == 0) { binbase_g[tid] = excl; bintotal_g[tid] = total; }
    }
    __syncthreads();
    for (int it = 0; it < 16; ++it) {
        int li = it * 320 + tid;
        if (li < EPSB) {
            int e = blk * EPSB + li;
            int d = dst[e];
            int b = d >> 6;
            int r = atomicAdd(&rank[b], 1);             // LDS atomic
            sorted[binbase[b] + r] = ((unsigned long long)(unsigned)d << 32) | (unsigned)src[e];
        }
    }
}

// ---------------- Layer-1 MFMA GEMM (1884 blocks, 64x128 tile, dbuf) + sort-pass4 tail (313) ----------------
#define GEMM1_BLOCKS 1884
#define PASS4_BLOCKS 313
__global__ __launch_bounds__(256) void k_gemm_l1_mfma(
    const unsigned short* __restrict__ xb,   // [N_PAD][256] bf16
    const unsigned short* __restrict__ wt,   // [768][256] bf16
    const float* __restrict__ bs, const float* __restrict__ bd, const float* __restrict__ br,
    unsigned short* __restrict__ fs, unsigned short* __restrict__ fd, unsigned short* __restrict__ res,
    const unsigned long long* __restrict__ sorted,
    const int* __restrict__ binbase_g, const int* __restrict__ bintotal_g,
    int* __restrict__ colp, int* __restrict__ cnt)
{
    __shared__ __align__(16) unsigned short SH[12288];  // 24KB: 2 x (As 4KB | Bs 8KB); C-tile 16KB
    int t = threadIdx.x;
    int bid = blockIdx.x;

    if (bid >= GEMM1_BLOCKS) {                  // ---- pass4 tail: per-bin node bucketing ----
        int* ch = (int*)SH;
        int nb2 = bid - GEMM1_BLOCKS;
        if (t < 64) ch[t] = 0;
        __syncthreads();
        int base = binbase_g[nb2], tot = bintotal_g[nb2];
        for (int i = t; i < tot; i += 256) {
            unsigned long long p = sorted[base + i];
            int d = (int)(p >> 32);
            int s = (int)(p & 0xffffffffULL);
            int r = atomicAdd(&ch[d & 63], 1);          // LDS atomic
            if (r < MAXDEG) colp[(size_t)d * MAXDEG + r] = s;
        }
        __syncthreads();
        int node = nb2 * 64 + t;
        if (t < 64 && node < N_NODES) cnt[node] = ch[t];
        return;
    }

    int lane = t & 63, w = t >> 6;
    // bijective XCD swizzle (m204): 1884 = 8*235 + 4
    const int q = 235, r = 4;
    int xcd = bid & 7, slot = bid >> 3;
    int wg = (xcd < r ? xcd * (q + 1) : r * (q + 1) + (xcd - r) * q) + slot;
    int mb = wg / 6, nb = wg % 6;
    int row0 = mb * 64;
    int which = nb >> 1;
    int col0 = (nb & 1) * 128;
    int ncol0 = nb * 128;
    unsigned short* out = (which == 0) ? fs : ((which == 1) ? fd : res);
    const float* bias   = (which == 0) ? bs : ((which == 1) ? bd : br);

    auto stage = [&](int buf, int k0) {
        char* base = (char*)SH + buf * 12288;
        {   // As: 64 rows x 32 k = 256 chunks
            int c = t, row = c >> 2, kc = (c & 3) * 8;
            gload16(xb + (size_t)(row0 + row) * 256 + k0 + kc, base + c * 16);
        }
#pragma unroll
        for (int r2 = 0; r2 < 2; r2++) {  // Bs: 128 rows x 32 k = 512 chunks
            int c = r2 * 256 + t, row = c >> 2, kc = (c & 3) * 8;
            gload16(wt + (size_t)(ncol0 + row) * 256 + k0 + kc, base + 4096 + c * 16);
        }
    };

    f32x4 acc[4][2] = {};

    stage(0, 0);
    __syncthreads();
    int cur = 0;
#pragma unroll
    for (int it = 0; it < 8; ++it) {
        if (it < 7) stage(cur ^ 1, (it + 1) * 32);   // issue next tile BEFORE compute
        const char* Ab = (const char*)SH + cur * 12288;
        const char* Bb = Ab + 4096;
        short8 a[4], b[2];
#pragma unroll
        for (int m = 0; m < 4; m++)
            a[m] = *reinterpret_cast<const short8*>(Ab + ((m * 16 + (lane & 15)) * 64 + (lane >> 4) * 16));
#pragma unroll
        for (int n = 0; n < 2; n++)
            b[n] = *reinterpret_cast<const short8*>(Bb + ((w * 32 + n * 16 + (lane & 15)) * 64 + (lane >> 4) * 16));
#pragma unroll
        for (int m = 0; m < 4; m++)
#pragma unroll
            for (int n = 0; n < 2; n++)
                acc[m][n] = __builtin_amdgcn_mfma_f32_16x16x32_bf16(a[m], b[n], acc[m][n], 0, 0, 0);
        __syncthreads();
        cur ^= 1;
    }

    // ---- epilogue: LDS-staged coalesced bf16 C-write (64 rows x 256B), single pass ----
    int cgrp = lane >> 4, ccol = lane & 15;
    float bvals[2];
#pragma unroll
    for (int n = 0; n < 2; n++) bvals[n] = bias[col0 + w * 32 + n * 16 + ccol];

#pragma unroll
    for (int m = 0; m < 4; m++)
#pragma unroll
        for (int n = 0; n < 2; n++)
#pragma unroll
            for (int q2 = 0; q2 < 4; q2++) {
                int lr = m * 16 + cgrp * 4 + q2;                     // 0..63
                int cb = (w * 32 + n * 16 + ccol) * 2;               // col byte 0..255
                int addr = lr * 256 + (cb ^ (cgrp << 5));            // bank-spread XOR
                *(unsigned short*)((char*)SH + addr) = f2b(acc[m][n][q2] + bvals[n]);
            }
    __syncthreads();
#pragma unroll
    for (int it = 0; it < 4; it++) {
        int lr = it * 16 + (t >> 4);                                 // 0..63
        int cb = (t & 15) * 16;
        short8 v = *(const short8*)((const char*)SH + (lr * 256 + (cb ^ (((lr >> 2) & 3) << 5))));
        int gr = row0 + lr;
        if (gr < N_NODES)
            *reinterpret_cast<short8*>(out + (size_t)gr * 256 + col0 + (t & 15) * 8) = v;
    }
}

// ---------------- Layer-1 gather: 1 wave/node, TWO independent online-softmax streams ----------------
__global__ __launch_bounds__(64) void k_gather_l1(
    const int* __restrict__ cnt, const int* __restrict__ colp,
    const unsigned short* __restrict__ fs1, const unsigned short* __restrict__ fd1,
    const unsigned short* __restrict__ res1, const float* __restrict__ attn1,
    unsigned short* __restrict__ y)
{
    int n = blockIdx.x;
    int l = threadIdx.x;          // lane: dims [4l,4l+4), head = l>>3
    u16x4 fdv4 = *reinterpret_cast<const u16x4*>(fd1 + (size_t)n * 256 + l * 4);
    float fdv[4] = {b2f(fdv4[0]), b2f(fdv4[1]), b2f(fdv4[2]), b2f(fdv4[3])};
    float4 attv = *reinterpret_cast<const float4*>(attn1 + l * 4);
    float att[4] = {attv.x, attv.y, attv.z, attv.w};

    const int* colrow = colp + (size_t)n * MAXDEG;
    int deg = cnt[n];
    if (deg > MAXDEG) deg = MAXDEG;

    float mA = -1e30f, sA = 0.f, aA[4] = {0.f, 0.f, 0.f, 0.f};
    float mB = -1e30f, sB = 0.f, aB[4] = {0.f, 0.f, 0.f, 0.f};

    int cA0 = (0 < deg) ? colrow[0] : 0;
    int cB0 = (1 < deg) ? colrow[1] : 0;
    int cA1 = (2 < deg) ? colrow[2] : 0;
    int cB1 = (3 < deg) ? colrow[3] : 0;
    u16x4 fA  = *reinterpret_cast<const u16x4*>(fs1 + (size_t)cA0 * 256 + l * 4);
    u16x4 fB  = *reinterpret_cast<const u16x4*>(fs1 + (size_t)cB0 * 256 + l * 4);
    u16x4 fA2 = *reinterpret_cast<const u16x4*>(fs1 + (size_t)cA1 * 256 + l * 4);
    u16x4 fB2 = *reinterpret_cast<const u16x4*>(fs1 + (size_t)cB1 * 256 + l * 4);

    int idx = 0;
    for (; idx + 1 < deg; idx += 2) {
        u16x4 vA = fA, vB = fB;
        fA = fA2; fB = fB2;
        int nA = (idx + 4 < deg) ? colrow[idx + 4] : 0;
        int nB = (idx + 5 < deg) ? colrow[idx + 5] : 0;
        fA2 = *reinterpret_cast<const u16x4*>(fs1 + (size_t)nA * 256 + l * 4);
        fB2 = *reinterpret_cast<const u16x4*>(fs1 + (size_t)nB * 256 + l * 4);

        // ---- stream A ----
        float xa0 = b2f(vA[0]), xa1 = b2f(vA[1]), xa2 = b2f(vA[2]), xa3 = b2f(vA[3]);
        float ta0 = xa0 + fdv[0]; ta0 = ta0 > 0.f ? ta0 : NEG * ta0;
        float ta1 = xa1 + fdv[1]; ta1 = ta1 > 0.f ? ta1 : NEG * ta1;
        float ta2 = xa2 + fdv[2]; ta2 = ta2 > 0.f ? ta2 : NEG * ta2;
        float ta3 = xa3 + fdv[3]; ta3 = ta3 > 0.f ? ta3 : NEG * ta3;
        float pA = ta0 * att[0] + ta1 * att[1] + ta2 * att[2] + ta3 * att[3];
        // ---- stream B ----
        float xb0 = b2f(vB[0]), xb1 = b2f(vB[1]), xb2 = b2f(vB[2]), xb3 = b2f(vB[3]);
        float tb0 = xb0 + fdv[0]; tb0 = tb0 > 0.f ? tb0 : NEG * tb0;
        float tb1 = xb1 + fdv[1]; tb1 = tb1 > 0.f ? tb1 : NEG * tb1;
        float tb2 = xb2 + fdv[2]; tb2 = tb2 > 0.f ? tb2 : NEG * tb2;
        float tb3 = xb3 + fdv[3]; tb3 = tb3 > 0.f ? tb3 : NEG * tb3;
        float pB = tb0 * att[0] + tb1 * att[1] + tb2 * att[2] + tb3 * att[3];

        pA += __shfl_xor(pA, 1); pB += __shfl_xor(pB, 1);
        pA += __shfl_xor(pA, 2); pB += __shfl_xor(pB, 2);
        pA += __shfl_xor(pA, 4); pB += __shfl_xor(pB, 4);

        float mnA = fmaxf(mA, pA);
        float eA  = __expf(pA - mnA);
        float scA = __expf(mA - mnA);
        sA = sA * scA + eA;
        aA[0] = aA[0] * scA + eA * xa0;
        aA[1] = aA[1] * scA + eA * xa1;
        aA[2] = aA[2] * scA + eA * xa2;
        aA[3] = aA[3] * scA + eA * xa3;
        mA = mnA;

        float mnB = fmaxf(mB, pB);
        float eB  = __expf(pB - mnB);
        float scB = __expf(mB - mnB);
        sB = sB * scB + eB;
        aB[0] = aB[0] * scB + eB * xb0;
        aB[1] = aB[1] * scB + eB * xb1;
        aB[2] = aB[2] * scB + eB * xb2;
        aB[3] = aB[3] * scB + eB * xb3;
        mB = mnB;
    }
    if (idx < deg) {                      // odd tail -> stream A (edge deg-1 is in fA)
        float xa0 = b2f(fA[0]), xa1 = b2f(fA[1]), xa2 = b2f(fA[2]), xa3 = b2f(fA[3]);
        float ta0 = xa0 + fdv[0]; ta0 = ta0 > 0.f ? ta0 : NEG * ta0;
        float ta1 = xa1 + fdv[1]; ta1 = ta1 > 0.f ? ta1 : NEG * ta1;
        float ta2 = xa2 + fdv[2]; ta2 = ta2 > 0.f ? ta2 : NEG * ta2;
        float ta3 = xa3 + fdv[3]; ta3 = ta3 > 0.f ? ta3 : NEG * ta3;
        float pA = ta0 * att[0] + ta1 * att[1] + ta2 * att[2] + ta3 * att[3];
        pA += __shfl_xor(pA, 1);
        pA += __shfl_xor(pA, 2);
        pA += __shfl_xor(pA, 4);
        float mnA = fmaxf(mA, pA);
        float eA  = __expf(pA - mnA);
        float scA = __expf(mA - mnA);
        sA = sA * scA + eA;
        aA[0] = aA[0] * scA + eA * xa0;
        aA[1] = aA[1] * scA + eA * xa1;
        aA[2] = aA[2] * scA + eA * xa2;
        aA[3] = aA[3] * scA + eA * xa3;
        mA = mnA;
    }
    // ---- merge streams ----
    float mn = fmaxf(mA, mB);
    float scA = __expf(mA - mn), scB = __expf(mB - mn);
    float s = sA * scA + sB * scB;
    float a0 = aA[0] * scA + aB[0] * scB;
    float a1 = aA[1] * scA + aB[1] * scB;
    float a2 = aA[2] * scA + aB[2] * scB;
    float a3 = aA[3] * scA + aB[3] * scB;

    u16x4 rv4 = *reinterpret_cast<const u16x4*>(res1 + (size_t)n * 256 + l * 4);
    float inv = (s > 0.f) ? 1.f / s : 0.f;
    u16x4 o;
    o[0] = f2b(fmaxf(a0 * inv + b2f(rv4[0]), 0.f));
    o[1] = f2b(fmaxf(a1 * inv + b2f(rv4[1]), 0.f));
    o[2] = f2b(fmaxf(a2 * inv + b2f(rv4[2]), 0.f));
    o[3] = f2b(fmaxf(a3 * inv + b2f(rv4[3]), 0.f));
    *reinterpret_cast<u16x4*>(y + (size_t)n * 256 + l * 4) = o;
}

// ---------------- Layer-2 MFMA GEMM: 64-row tiles, 2-phase dbuf A, B resident ----------------
__global__ __launch_bounds__(256) void k_gemm_l2_mfma(
    const unsigned short* __restrict__ yb,   // [N_PAD][256] bf16
    const unsigned short* __restrict__ wt2,  // [96][256] bf16, pre-swizzled
    const float* __restrict__ bs, const float* __restrict__ bd, const float* __restrict__ br,
    unsigned short* __restrict__ fs2, unsigned short* __restrict__ fd2, unsigned short* __restrict__ res2)
{
    __shared__ __align__(16) unsigned short Bs[96 * 256];   // 48 KB, whole WT2
    __shared__ __align__(16) unsigned short As[2][64 * 32]; // 2 x 4 KB
    int t = threadIdx.x;
    int lane = t & 63, w = t >> 6;
    int row0 = blockIdx.x * 64;

    auto stage_a = [&](int buf, int k0) {
        int c = t;
        int row = c >> 2, kc = (c & 3) * 8;
        gload16(yb + (size_t)(row0 + row) * 256 + k0 + kc, (char*)As[buf] + c * 16);
    };

#pragma unroll
    for (int i = 0; i < 12; i++) {
        int c = i * 256 + t;
        gload16(wt2 + (size_t)c * 8, (char*)Bs + (size_t)c * 16);
    }
    stage_a(0, 0);
    __syncthreads();

    f32x4 acc[6] = {};
    int arow0 = w * 16;
    int cur = 0;

#pragma unroll
    for (int it = 0; it < 8; ++it) {
        if (it < 7) stage_a(cur ^ 1, (it + 1) * 32);
        short8 a = *reinterpret_cast<const short8*>((const char*)As[cur] + ((arow0 + (lane & 15)) * 64 + (lane >> 4) * 16));
        short8 b[6];
#pragma unroll
        for (int n = 0; n < 6; n++) {
            int brow = n * 16 + (lane & 15);
            int kbyte = (it * 32 + (lane >> 4) * 8) * 2;
            b[n] = *reinterpret_cast<const short8*>((const char*)Bs + (brow * 512 + (kbyte ^ ((brow & 7) << 4))));
        }
#pragma unroll
        for (int n = 0; n < 6; n++)
            acc[n] = __builtin_amdgcn_mfma_f32_16x16x32_bf16(a, b[n], acc[n], 0, 0, 0);
        __syncthreads();
        cur ^= 1;
    }

    int cgrp = lane >> 4, ccol = lane & 15;
#pragma unroll
    for (int n = 0; n < 6; n++) {
        int which = n >> 1;
        int cc = (n & 1) * 16 + ccol;
        unsigned short* out = (which == 0) ? fs2 : ((which == 1) ? fd2 : res2);
        const float* bias   = (which == 0) ? bs  : ((which == 1) ? bd  : br);
        float bv = bias[cc];
        int rbase = row0 + arow0 + cgrp * 4;
#pragma unroll
        for (int q2 = 0; q2 < 4; q2++) {
            int rr = rbase + q2;
            if (rr < N_NODES) out[(size_t)rr * 32 + cc] = f2b(acc[n][q2] + bv);
        }
    }
}

// ---------------- Layer-2 gather: 1 wave/node, 2 edges/iter (per-half streams), prefetched ----------------
__global__ __launch_bounds__(64) void k_gather_l2(
    const int* __restrict__ cnt, const int* __restrict__ colp,
    const unsigned short* __restrict__ fs2, const unsigned short* __restrict__ fd2,
    const unsigned short* __restrict__ res2, const float* __restrict__ attn2,
    float* __restrict__ out)
{
    int n = blockIdx.x;
    int l = threadIdx.x;
    int d = l & 31, h = l >> 5;
    float fdv = b2f(fd2[(size_t)n * 32 + d]);
    float att = attn2[d];
    const int* colrow = colp + (size_t)n * MAXDEG;
    int deg = cnt[n];
    if (deg > MAXDEG) deg = MAXDEG;

    float m = -1e30f, s = 0.f, acc = 0.f;
    int c0 = (h < deg) ? colrow[h] : 0;
    float fv_next = b2f(fs2[(size_t)c0 * 32 + d]);
    for (int i = h; i < deg; i += 2) {
        float fv = fv_next;
        int cn = (i + 2 < deg) ? colrow[i + 2] : 0;
        fv_next = b2f(fs2[(size_t)cn * 32 + d]);
        float t0 = fv + fdv; t0 = t0 > 0.f ? t0 : NEG * t0;
        float p = t0 * att;
        p += __shfl_xor(p, 1);
        p += __shfl_xor(p, 2);
        p += __shfl_xor(p, 4);
        p += __shfl_xor(p, 8);
        p += __shfl_xor(p, 16);
        float mn = fmaxf(m, p);
        float e  = __expf(p - mn);
        float sc = __expf(m - mn);
        s = s * sc + e;
        acc = acc * sc + e * fv;
        m = mn;
    }
    float mo = __shfl_xor(m, 32);
    float mstar = fmaxf(m, mo);
    float myc = __expf(m - mstar);
    float sp = s * myc, ap = acc * myc;
    float st = sp + __shfl_xor(sp, 32);
    float at = ap + __shfl_xor(ap, 32);
    if (l < 32) {
        float rv = b2f(res2[(size_t)n * 32 + d]);
        float inv = (st > 0.f) ? 1.f / st : 0.f;
        out[(size_t)n * 32 + d] = at * inv + rv;
    }
}

extern "C" void kernel_launch(void* const* d_in, const int* in_sizes, int n_in,
                              void* d_out, int out_size, void* d_ws, size_t ws_size,
                              hipStream_t stream)
{
    const float* x   = (const float*)d_in[0];
    const int*   src = (const int*)d_in[1];
    const int*   dst = (const int*)d_in[2];
    const float* Ws1 = (const float*)d_in[3];
    const float* bs1 = (const float*)d_in[4];
    const float* Wd1 = (const float*)d_in[5];
    const float* bd1 = (const float*)d_in[6];
    const float* at1 = (const float*)d_in[7];
    const float* Wr1 = (const float*)d_in[8];
    const float* br1 = (const float*)d_in[9];
    const float* Ws2 = (const float*)d_in[10];
    const float* bs2 = (const float*)d_in[11];
    const float* Wd2 = (const float*)d_in[12];
    const float* bd2 = (const float*)d_in[13];
    const float* at2 = (const float*)d_in[14];
    const float* Wr2 = (const float*)d_in[15];
    const float* br2 = (const float*)d_in[16];
    float* out = (float*)d_out;

    char* w = (char*)d_ws;
    size_t off = 0;
    auto alloc = [&](size_t bytes) { void* p = w + off; off += (bytes + 255) & ~(size_t)255; return p; };
    int*   cnt       = (int*)  alloc((size_t)N_NODES * 4);
    int*   colp      = (int*)  alloc((size_t)N_NODES * MAXDEG * 4);
    int*   blockhist = (int*)  alloc((size_t)NSB * NBIN * 4);
    int*   bintotal  = (int*)  alloc((size_t)NBIN * 4);
    int*   binbase   = (int*)  alloc((size_t)NBIN * 4);
    unsigned long long* sorted = (unsigned long long*)alloc((size_t)N_EDGES * 8);
    unsigned short* fs1 = (unsigned short*)alloc((size_t)N_NODES * 256 * 2);
    unsigned short* fd1 = (unsigned short*)alloc((size_t)N_NODES * 256 * 2);
    unsigned short* res1= (unsigned short*)alloc((size_t)N_NODES * 256 * 2);
    unsigned short* fs2 = (unsigned short*)alloc((size_t)N_NODES * 32 * 2);
    unsigned short* fd2 = (unsigned short*)alloc((size_t)N_NODES * 32 * 2);
    unsigned short* res2= (unsigned short*)alloc((size_t)N_NODES * 32 * 2);
    unsigned short* xb  = (unsigned short*)alloc((size_t)N_PAD * 256 * 2);
    unsigned short* yb  = (unsigned short*)alloc((size_t)N_PAD * 256 * 2);
    unsigned short* wt  = (unsigned short*)alloc((size_t)768 * 256 * 2);
    unsigned short* wt2 = (unsigned short*)alloc((size_t)96 * 256 * 2);
    (void)ws_size; (void)in_sizes; (void)n_in; (void)out_size;

    k_prep<<<PREP_BLOCKS, 256, 0, stream>>>(x, xb, Ws1, Wd1, Wr1, wt, Ws2, Wd2, Wr2, wt2,
                                            dst, blockhist, yb);
    k_pass3<<<NSB, 320, 0, stream>>>(src, dst, blockhist, sorted, binbase, bintotal);
    k_gemm_l1_mfma<<<GEMM1_BLOCKS + PASS4_BLOCKS, 256, 0, stream>>>(
        xb, wt, bs1, bd1, br1, fs1, fd1, res1, sorted, binbase, bintotal, colp, cnt);
    k_gather_l1<<<N_NODES, 64, 0, stream>>>(cnt, colp, fs1, fd1, res1, at1, yb);
    k_gemm_l2_mfma<<<N_PAD / 64, 256, 0, stream>>>(yb, wt2, bs2, bd2, br2, fs2, fd2, res2);
    k_gather_l2<<<N_NODES, 64, 0, stream>>>(cnt, colp, fs2, fd2, res2, at2, out);
}